// Round 8
// baseline (830.104 us; speedup 1.0000x reference)
//
#include <hip/hip_runtime.h>
#include <hip/hip_bf16.h>
#include <cstddef>

#define NN 50000
#define EE 800000
#define NB ((NN + 255) / 256)

typedef __attribute__((ext_vector_type(8))) short short8;
typedef __attribute__((ext_vector_type(4))) float f32x4;

__device__ __forceinline__ float leaky(float x) { return x >= 0.f ? x : 0.2f * x; }
__device__ __forceinline__ float bf2f(unsigned short u) {
  return __uint_as_float(((unsigned int)u) << 16);
}
__device__ __forceinline__ float bflo(unsigned int v) { return __uint_as_float(v << 16); }
__device__ __forceinline__ float bfhi(unsigned int v) { return __uint_as_float(v & 0xFFFF0000u); }
__device__ __forceinline__ unsigned short f2bf(float f) {
  __hip_bfloat16 b = __float2bfloat16(f);
  return __builtin_bit_cast(unsigned short, b);
}
__device__ __forceinline__ void accum8(float a, uint4 v, float* acc) {
  acc[0] += a * bflo(v.x); acc[1] += a * bfhi(v.x);
  acc[2] += a * bflo(v.y); acc[3] += a * bfhi(v.y);
  acc[4] += a * bflo(v.z); acc[5] += a * bfhi(v.z);
  acc[6] += a * bflo(v.w); acc[7] += a * bfhi(v.w);
}

// ==== bf16 MFMA GEMM + fused attention-logit epilogue =======================
// C[m,n] = sum_k A[m,k]*Bt[n,k]; tile 128x64, 4 waves. The column block bn
// covers exactly one head (64 ch), so als/ald/selfex for head bn>>6 are
// computed here from the SAME bf16-rounded h values that are stored.
__global__ __launch_bounds__(256) void gemm_bf16_k(const unsigned short* __restrict__ A,
                                                   const unsigned short* __restrict__ Bt,
                                                   unsigned short* __restrict__ Cb,
                                                   int K, int Nfull,
                                                   const float* __restrict__ a_s,
                                                   const float* __restrict__ a_d,
                                                   float* __restrict__ als,
                                                   float* __restrict__ ald,
                                                   float* __restrict__ selfex) {
  __shared__ __align__(16) unsigned short As[128 * 40];
  __shared__ __align__(16) unsigned short Bs[64 * 40];
  const int tid = threadIdx.x;
  const int lane = tid & 63;
  const int w = tid >> 6;
  const int bm = blockIdx.x * 128;
  const int bn = blockIdx.y * 64;
  const int quad = lane >> 4;
  const int l16 = lane & 15;
  f32x4 acc[2][4] = {};
  for (int kc = 0; kc < K; kc += 32) {
    {
      int row = tid >> 2, seg = tid & 3;
      int sr = bm + row; if (sr >= NN) sr = NN - 1;
      *(uint4*)&As[row * 40 + seg * 8] = *(const uint4*)(A + (size_t)sr * K + kc + seg * 8);
      row = (tid + 256) >> 2; seg = (tid + 256) & 3;
      sr = bm + row; if (sr >= NN) sr = NN - 1;
      *(uint4*)&As[row * 40 + seg * 8] = *(const uint4*)(A + (size_t)sr * K + kc + seg * 8);
      int n = tid >> 2; seg = tid & 3;
      *(uint4*)&Bs[n * 40 + seg * 8] = *(const uint4*)(Bt + (size_t)(bn + n) * K + kc + seg * 8);
    }
    __syncthreads();
    short8 afr0 = *(const short8*)&As[(w * 32 + l16) * 40 + quad * 8];
    short8 afr1 = *(const short8*)&As[(w * 32 + 16 + l16) * 40 + quad * 8];
#pragma unroll
    for (int nt = 0; nt < 4; ++nt) {
      short8 bfr = *(const short8*)&Bs[(nt * 16 + l16) * 40 + quad * 8];
      acc[0][nt] = __builtin_amdgcn_mfma_f32_16x16x32_bf16(afr0, bfr, acc[0][nt], 0, 0, 0);
      acc[1][nt] = __builtin_amdgcn_mfma_f32_16x16x32_bf16(afr1, bfr, acc[1][nt], 0, 0, 0);
    }
    __syncthreads();
  }
  const int head = bn >> 6;
  const int Hmul = Nfull >> 6;
  float vs[2][4] = {};
  float vd[2][4] = {};
#pragma unroll
  for (int nt = 0; nt < 4; ++nt) {
    const float asv = a_s[head * 64 + nt * 16 + l16];
    const float adv = a_d[head * 64 + nt * 16 + l16];
#pragma unroll
    for (int mt = 0; mt < 2; ++mt)
#pragma unroll
      for (int reg = 0; reg < 4; ++reg) {
        unsigned short c = f2bf(acc[mt][nt][reg]);
        int r = bm + w * 32 + mt * 16 + quad * 4 + reg;
        if (r < NN) Cb[(size_t)r * Nfull + bn + nt * 16 + l16] = c;
        float hv = bf2f(c);
        vs[mt][reg] += hv * asv;
        vd[mt][reg] += hv * adv;
      }
  }
#pragma unroll
  for (int off = 1; off < 16; off <<= 1) {
#pragma unroll
    for (int mt = 0; mt < 2; ++mt)
#pragma unroll
      for (int reg = 0; reg < 4; ++reg) {
        vs[mt][reg] += __shfl_xor(vs[mt][reg], off, 64);
        vd[mt][reg] += __shfl_xor(vd[mt][reg], off, 64);
      }
  }
  if (l16 == 0) {
#pragma unroll
    for (int mt = 0; mt < 2; ++mt)
#pragma unroll
      for (int reg = 0; reg < 4; ++reg) {
        int r = bm + w * 32 + mt * 16 + quad * 4 + reg;
        if (r < NN) {
          als[(size_t)r * Hmul + head] = vs[mt][reg];
          ald[(size_t)r * Hmul + head] = vd[mt][reg];
          selfex[(size_t)r * Hmul + head] = __expf(leaky(vs[mt][reg] + vd[mt][reg]));
        }
      }
  }
}

// ================= CSR build (topology is layer-invariant) ==================
__global__ __launch_bounds__(256) void hist_k(const int* __restrict__ ei, int* deg) {
  int i = blockIdx.x * 256 + threadIdx.x;
  if (i < EE) atomicAdd(&deg[ei[EE + i]], 1);
}

__global__ __launch_bounds__(256) void scan1_k(const int* __restrict__ deg,
                                               int* __restrict__ incl,
                                               int* __restrict__ partial) {
  __shared__ int s[256];
  int t = threadIdx.x;
  int i = blockIdx.x * 256 + t;
  int v = (i < NN) ? deg[i] : 0;
  s[t] = v;
  __syncthreads();
  for (int off = 1; off < 256; off <<= 1) {
    int u = (t >= off) ? s[t - off] : 0;
    __syncthreads();
    s[t] += u;
    __syncthreads();
  }
  if (i < NN) incl[i] = s[t];
  if (t == 255) partial[blockIdx.x] = s[255];
}

__global__ void scan2_k(int* __restrict__ partial) {
  __shared__ int s[256];
  int t = threadIdx.x;
  int v = (t < NB) ? partial[t] : 0;
  s[t] = v;
  __syncthreads();
  for (int off = 1; off < 256; off <<= 1) {
    int u = (t >= off) ? s[t - off] : 0;
    __syncthreads();
    s[t] += u;
    __syncthreads();
  }
  if (t < NB) partial[t] = s[t] - v;  // exclusive
}

__global__ __launch_bounds__(256) void scan3_k(const int* __restrict__ deg,
                                               const int* __restrict__ incl,
                                               const int* __restrict__ partial,
                                               int* __restrict__ rowptr,
                                               int* __restrict__ cursor) {
  int i = blockIdx.x * 256 + threadIdx.x;
  if (i >= NN) return;
  int r = partial[blockIdx.x] + incl[i] - deg[i];
  rowptr[i] = r;
  cursor[i] = r;
}

__global__ __launch_bounds__(256) void scatter_k(const int* __restrict__ ei,
                                                 int* __restrict__ cursor,
                                                 int* __restrict__ csr_src,
                                                 int* __restrict__ csr_dst) {
  int i = blockIdx.x * 256 + threadIdx.x;
  if (i >= EE) return;
  int d = ei[EE + i];
  int p = atomicAdd(&cursor[d], 1);
  csr_src[p] = ei[i];
  csr_dst[p] = d;
}

// ====== per-CSR-slot unnormalized exp, SoA planes ex[h][i] (H=4) ============
__global__ __launch_bounds__(256) void edge_exp4_k(const int* __restrict__ csr_src,
                                                   const int* __restrict__ csr_dst,
                                                   const float* __restrict__ als,
                                                   const float* __restrict__ ald,
                                                   float* __restrict__ ex) {
  int i = blockIdx.x * 256 + threadIdx.x;
  if (i >= EE) return;
  int s = csr_src[i], d = csr_dst[i];
  const float4 as4 = *(const float4*)(als + (size_t)s * 4);
  const float4 ad4 = *(const float4*)(ald + (size_t)d * 4);
  ex[i] = __expf(leaky(as4.x + ad4.x));
  ex[EE + i] = __expf(leaky(as4.y + ad4.y));
  ex[2 * EE + i] = __expf(leaky(as4.z + ad4.z));
  ex[3 * EE + i] = __expf(leaky(as4.w + ad4.w));
}

__global__ __launch_bounds__(256) void edge_exp1_k(const int* __restrict__ csr_src,
                                                   const int* __restrict__ csr_dst,
                                                   const float* __restrict__ als,
                                                   const float* __restrict__ ald,
                                                   float* __restrict__ ex1) {
  int i = blockIdx.x * 256 + threadIdx.x;
  if (i >= EE) return;
  ex1[i] = __expf(leaky(als[csr_src[i]] + ald[csr_dst[i]]));
}

// ====== XCD-sliced gather-aggregate, H=4 =====================================
// slice = blockIdx&7 (rides round-robin block->XCD mapping): each XCD touches
// only 50000x64B = 3.2MB of h -> L2-resident gathers. Wave/dst: 16 edge-slots
// x 4 lanes x 8ch. den-sum inlined (reduced over slot bits only). Zero atomics.
__global__ __launch_bounds__(256) void aggr4s_k(const int* __restrict__ rowptr,
                                                const int* __restrict__ deg,
                                                const int* __restrict__ csr_src,
                                                const float* __restrict__ ex,
                                                const float* __restrict__ selfex,
                                                const uint4* __restrict__ hb4,
                                                const float* __restrict__ bias,
                                                uint4* __restrict__ out4) {
  const int slice = blockIdx.x & 7;
  const int grp = blockIdx.x >> 3;
  const int dst = grp * 4 + (threadIdx.x >> 6);
  const int lane = threadIdx.x & 63;
  const int slot = lane >> 2;
  const int c4 = lane & 3;
  const int colU = slice * 4 + c4;        // uint4 index within the 32-uint4 row
  const int head = slice >> 1;
  const float* __restrict__ exh = ex + (size_t)head * EE;
  const int rs = rowptr[dst];
  const int dg = deg[dst];
  const float sx = selfex[dst * 4 + head];

  float acc[8] = {};
  float dsum = 0.f;
  if (slot == 0) {  // self-loop: each c4 lane covers its own 8 channels once
    uint4 v = hb4[(size_t)dst * 32 + colU];
    accum8(sx, v, acc);
  }
  for (int j = slot; j < dg; j += 16) {
    int s = csr_src[rs + j];
    float a = exh[rs + j];
    uint4 v = hb4[(size_t)s * 32 + colU];
    dsum += a;
    accum8(a, v, acc);
  }
  // reduce over slot bits (2..5) only; c4 lanes keep distinct channel chunks
#pragma unroll
  for (int off = 4; off < 64; off <<= 1) {
#pragma unroll
    for (int k = 0; k < 8; ++k) acc[k] += __shfl_xor(acc[k], off, 64);
    dsum += __shfl_xor(dsum, off, 64);
  }
  if (slot == 0) {
    const float inv = 1.f / (dsum + sx + 1e-16f);
    const float4 bz0 = *(const float4*)(bias + colU * 8);
    const float4 bz1 = *(const float4*)(bias + colU * 8 + 4);
    float c0, c1;
    uint4 o;
    c0 = fmaxf(acc[0] * inv + bz0.x, 0.f); c1 = fmaxf(acc[1] * inv + bz0.y, 0.f);
    o.x = ((unsigned int)f2bf(c1) << 16) | f2bf(c0);
    c0 = fmaxf(acc[2] * inv + bz0.z, 0.f); c1 = fmaxf(acc[3] * inv + bz0.w, 0.f);
    o.y = ((unsigned int)f2bf(c1) << 16) | f2bf(c0);
    c0 = fmaxf(acc[4] * inv + bz1.x, 0.f); c1 = fmaxf(acc[5] * inv + bz1.y, 0.f);
    o.z = ((unsigned int)f2bf(c1) << 16) | f2bf(c0);
    c0 = fmaxf(acc[6] * inv + bz1.z, 0.f); c1 = fmaxf(acc[7] * inv + bz1.w, 0.f);
    o.w = ((unsigned int)f2bf(c1) << 16) | f2bf(c0);
    out4[(size_t)dst * 32 + colU] = o;
  }
}

// ====== XCD-sliced gather-aggregate, H=1 (8 slices x 8ch, 64 edge slots) ====
__global__ __launch_bounds__(256) void aggr1s_k(const int* __restrict__ rowptr,
                                                const int* __restrict__ deg,
                                                const int* __restrict__ csr_src,
                                                const float* __restrict__ ex1,
                                                const float* __restrict__ selfex,
                                                const uint4* __restrict__ hb4,
                                                const float* __restrict__ bias,
                                                float* __restrict__ out) {
  const int slice = blockIdx.x & 7;
  const int grp = blockIdx.x >> 3;
  const int dst = grp * 4 + (threadIdx.x >> 6);
  const int lane = threadIdx.x & 63;
  const int rs = rowptr[dst];
  const int dg = deg[dst];
  const float sx = selfex[dst];

  float acc[8] = {};
  float dsum = 0.f;
  if (lane == 0) {
    uint4 v = hb4[(size_t)dst * 8 + slice];
    accum8(sx, v, acc);
  }
  for (int j = lane; j < dg; j += 64) {
    int s = csr_src[rs + j];
    float a = ex1[rs + j];
    uint4 v = hb4[(size_t)s * 8 + slice];
    dsum += a;
    accum8(a, v, acc);
  }
#pragma unroll
  for (int off = 1; off < 64; off <<= 1) {
#pragma unroll
    for (int k = 0; k < 8; ++k) acc[k] += __shfl_xor(acc[k], off, 64);
    dsum += __shfl_xor(dsum, off, 64);
  }
  if (lane == 0) {  // no relu on layer 2; fp32 out, 32B chunk
    const float inv = 1.f / (dsum + sx + 1e-16f);
    const float4 bz0 = *(const float4*)(bias + slice * 8);
    const float4 bz1 = *(const float4*)(bias + slice * 8 + 4);
    float4 o0 = make_float4(acc[0] * inv + bz0.x, acc[1] * inv + bz0.y,
                            acc[2] * inv + bz0.z, acc[3] * inv + bz0.w);
    float4 o1 = make_float4(acc[4] * inv + bz1.x, acc[5] * inv + bz1.y,
                            acc[6] * inv + bz1.z, acc[7] * inv + bz1.w);
    *(float4*)(out + (size_t)dst * 64 + slice * 8) = o0;
    *(float4*)(out + (size_t)dst * 64 + slice * 8 + 4) = o1;
  }
}

// ---- prep: fp32 x -> packed bf16 ----
__global__ __launch_bounds__(256) void castx_k(const float2* __restrict__ x2,
                                               unsigned int* __restrict__ xb_u) {
  int i = blockIdx.x * 256 + threadIdx.x;
  if (i >= NN * 64) return;
  float2 v = x2[i];
  xb_u[i] = ((unsigned int)f2bf(v.y) << 16) | f2bf(v.x);
}

// ---- prep: W[K][N] fp32 -> Wt[N][K] bf16 ----
__global__ __launch_bounds__(64) void trw_k(const float* __restrict__ W,
                                            unsigned short* __restrict__ Wt, int K, int N) {
  int k = blockIdx.x;
  int n = blockIdx.y * 64 + threadIdx.x;
  Wt[(size_t)n * K + k] = f2bf(W[(size_t)k * N + n]);
}

// column sums of final [N,64] fp32 -> g[64]
__global__ __launch_bounds__(256) void colsum_k(const float* __restrict__ h2,
                                                float* __restrict__ g) {
  __shared__ float s[256];
  int tid = threadIdx.x;
  int c = tid & 63, rg = tid >> 6;
  float acc = 0.f;
  for (int n = blockIdx.x * 4 + rg; n < NN; n += gridDim.x * 4)
    acc += h2[n * 64 + c];
  s[tid] = acc;
  __syncthreads();
  if (tid < 64) atomicAdd(&g[c], s[c] + s[64 + c] + s[128 + c] + s[192 + c]);
}

__global__ void head_k(const float* __restrict__ g, const float* __restrict__ hw,
                       const float* __restrict__ hb, float* __restrict__ out) {
  int o = threadIdx.x;  // 64 threads
  float acc = 0.f;
  const float invN = 1.0f / (float)NN;
#pragma unroll 8
  for (int c = 0; c < 64; ++c) acc += (g[c] * invN) * hw[c * 64 + o];
  out[o] = acc + hb[o];
}

extern "C" void kernel_launch(void* const* d_in, const int* in_sizes, int n_in,
                              void* d_out, int out_size, void* d_ws, size_t ws_size,
                              hipStream_t stream) {
  const float* x   = (const float*)d_in[0];
  const int*   ei  = (const int*)d_in[1];
  const float* W0  = (const float*)d_in[2];
  const float* a0s = (const float*)d_in[3];
  const float* a0d = (const float*)d_in[4];
  const float* b0  = (const float*)d_in[5];
  const float* W1  = (const float*)d_in[6];
  const float* a1s = (const float*)d_in[7];
  const float* a1d = (const float*)d_in[8];
  const float* b1  = (const float*)d_in[9];
  const float* W2  = (const float*)d_in[10];
  const float* a2s = (const float*)d_in[11];
  const float* a2d = (const float*)d_in[12];
  const float* b2  = (const float*)d_in[13];
  const float* hw  = (const float*)d_in[14];
  const float* hb  = (const float*)d_in[15];
  float* out = (float*)d_out;

  char* w = (char*)d_ws;
  unsigned short* xb   = (unsigned short*)w; w += (size_t)NN * 128 * 2;
  unsigned short* bufG = (unsigned short*)w; w += (size_t)NN * 256 * 2;
  unsigned short* bufA = (unsigned short*)w; w += (size_t)NN * 256 * 2;
  float* bufF = (float*)w;                   w += (size_t)NN * 64 * 4;
  unsigned short* W0t = (unsigned short*)w;  w += 256 * 128 * 2;
  unsigned short* W1t = (unsigned short*)w;  w += 256 * 256 * 2;
  unsigned short* W2t = (unsigned short*)w;  w += 64 * 256 * 2;
  float* als  = (float*)w;    w += (size_t)NN * 4 * 4;
  float* ald  = (float*)w;    w += (size_t)NN * 4 * 4;
  float* sfx  = (float*)w;    w += (size_t)NN * 4 * 4;
  float* ex   = (float*)w;    w += (size_t)EE * 4 * 4;  // 4 SoA planes (or 1 for H=1)
  int* deg     = (int*)w;     w += (size_t)NN * 4;
  int* rowptr  = (int*)w;     w += (size_t)NN * 4;
  int* cursor  = (int*)w;     w += (size_t)NN * 4;
  int* incl    = (int*)w;     w += (size_t)NN * 4;
  int* partial = (int*)w;     w += 256 * 4;
  int* csr_src = (int*)w;     w += (size_t)EE * 4;
  int* csr_dst = (int*)w;     w += (size_t)EE * 4;
  float* g    = (float*)w;    w += 256;

  // ---- CSR build (shared by all 3 layers) ----
  hipMemsetAsync(deg, 0, (size_t)NN * 4, stream);
  hist_k<<<(EE + 255) / 256, 256, 0, stream>>>(ei, deg);
  scan1_k<<<NB, 256, 0, stream>>>(deg, incl, partial);
  scan2_k<<<1, 256, 0, stream>>>(partial);
  scan3_k<<<NB, 256, 0, stream>>>(deg, incl, partial, rowptr, cursor);
  scatter_k<<<(EE + 255) / 256, 256, 0, stream>>>(ei, cursor, csr_src, csr_dst);

  // ---- prep casts/transposes ----
  castx_k<<<(NN * 64 + 255) / 256, 256, 0, stream>>>((const float2*)x, (unsigned int*)xb);
  trw_k<<<dim3(128, 4), 64, 0, stream>>>(W0, W0t, 128, 256);
  trw_k<<<dim3(256, 4), 64, 0, stream>>>(W1, W1t, 256, 256);
  trw_k<<<dim3(256, 1), 64, 0, stream>>>(W2, W2t, 256, 64);

  const int GX = (NN + 127) / 128;
  const int GA8 = (NN / 4) * 8;  // 100000 blocks: slice = blockIdx&7
  const int GE = EE / 256;       // 3125 exact

  auto layer4 = [&](const unsigned short* in, int K, const unsigned short* Wt,
                    const float* a_s, const float* a_d, const float* bias,
                    unsigned short* hbuf, unsigned short* obuf) {
    gemm_bf16_k<<<dim3(GX, 4), 256, 0, stream>>>(in, Wt, hbuf, K, 256,
                                                 a_s, a_d, als, ald, sfx);
    edge_exp4_k<<<GE, 256, 0, stream>>>(csr_src, csr_dst, als, ald, ex);
    aggr4s_k<<<GA8, 256, 0, stream>>>(rowptr, deg, csr_src, ex, sfx,
                                      (const uint4*)hbuf, bias, (uint4*)obuf);
  };

  // layers 0 and 1 (H=4)
  layer4(xb, 128, W0t, a0s, a0d, b0, bufG, bufA);
  layer4(bufA, 256, W1t, a1s, a1d, b1, bufG, bufA);

  // layer 2 (H=1)
  gemm_bf16_k<<<dim3(GX, 1), 256, 0, stream>>>(bufA, W2t, bufG, 256, 64,
                                               a2s, a2d, als, ald, sfx);
  edge_exp1_k<<<GE, 256, 0, stream>>>(csr_src, csr_dst, als, ald, ex);
  aggr1s_k<<<GA8, 256, 0, stream>>>(rowptr, deg, csr_src, ex, sfx,
                                    (const uint4*)bufG, b2, bufF);

  hipMemsetAsync(g, 0, 64 * 4, stream);
  colsum_k<<<256, 256, 0, stream>>>(bufF, g);
  head_k<<<1, 64, 0, stream>>>(g, hw, hb, out);
}

// Round 9
// 451.628 us; speedup vs baseline: 1.8380x; 1.8380x over previous
//
#include <hip/hip_runtime.h>
#include <hip/hip_bf16.h>
#include <cstddef>

#define NN 50000
#define EE 800000
#define NB ((NN + 255) / 256)

typedef __attribute__((ext_vector_type(8))) short short8;
typedef __attribute__((ext_vector_type(4))) float f32x4;

__device__ __forceinline__ float leaky(float x) { return x >= 0.f ? x : 0.2f * x; }
__device__ __forceinline__ float bf2f(unsigned short u) {
  return __uint_as_float(((unsigned int)u) << 16);
}
__device__ __forceinline__ float bflo(unsigned int v) { return __uint_as_float(v << 16); }
__device__ __forceinline__ float bfhi(unsigned int v) { return __uint_as_float(v & 0xFFFF0000u); }
__device__ __forceinline__ unsigned short f2bf(float f) {
  __hip_bfloat16 b = __float2bfloat16(f);
  return __builtin_bit_cast(unsigned short, b);
}
__device__ __forceinline__ float selh(float4 v, int h) {
  float a = (h & 1) ? v.y : v.x;
  float b = (h & 1) ? v.w : v.z;
  return (h & 2) ? b : a;
}
__device__ __forceinline__ void accum8(float a, uint4 v, float* acc) {
  acc[0] += a * bflo(v.x); acc[1] += a * bfhi(v.x);
  acc[2] += a * bflo(v.y); acc[3] += a * bfhi(v.y);
  acc[4] += a * bflo(v.z); acc[5] += a * bfhi(v.z);
  acc[6] += a * bflo(v.w); acc[7] += a * bfhi(v.w);
}

// ==== bf16 MFMA GEMM + fused attention-logit epilogue =======================
// C[m,n] = sum_k A[m,k]*Bt[n,k]; tile 128x64, 4 waves. Column block bn covers
// exactly one head (64 ch), so als/ald/selfex for head bn>>6 are computed here
// from the SAME bf16-rounded h values that are stored (bit-identical).
__global__ __launch_bounds__(256) void gemm_bf16_k(const unsigned short* __restrict__ A,
                                                   const unsigned short* __restrict__ Bt,
                                                   unsigned short* __restrict__ Cb,
                                                   int K, int Nfull,
                                                   const float* __restrict__ a_s,
                                                   const float* __restrict__ a_d,
                                                   float* __restrict__ als,
                                                   float* __restrict__ ald,
                                                   float* __restrict__ selfex) {
  __shared__ __align__(16) unsigned short As[128 * 40];
  __shared__ __align__(16) unsigned short Bs[64 * 40];
  const int tid = threadIdx.x;
  const int lane = tid & 63;
  const int w = tid >> 6;
  const int bm = blockIdx.x * 128;
  const int bn = blockIdx.y * 64;
  const int quad = lane >> 4;
  const int l16 = lane & 15;
  f32x4 acc[2][4] = {};
  for (int kc = 0; kc < K; kc += 32) {
    {
      int row = tid >> 2, seg = tid & 3;
      int sr = bm + row; if (sr >= NN) sr = NN - 1;
      *(uint4*)&As[row * 40 + seg * 8] = *(const uint4*)(A + (size_t)sr * K + kc + seg * 8);
      row = (tid + 256) >> 2; seg = (tid + 256) & 3;
      sr = bm + row; if (sr >= NN) sr = NN - 1;
      *(uint4*)&As[row * 40 + seg * 8] = *(const uint4*)(A + (size_t)sr * K + kc + seg * 8);
      int n = tid >> 2; seg = tid & 3;
      *(uint4*)&Bs[n * 40 + seg * 8] = *(const uint4*)(Bt + (size_t)(bn + n) * K + kc + seg * 8);
    }
    __syncthreads();
    short8 afr0 = *(const short8*)&As[(w * 32 + l16) * 40 + quad * 8];
    short8 afr1 = *(const short8*)&As[(w * 32 + 16 + l16) * 40 + quad * 8];
#pragma unroll
    for (int nt = 0; nt < 4; ++nt) {
      short8 bfr = *(const short8*)&Bs[(nt * 16 + l16) * 40 + quad * 8];
      acc[0][nt] = __builtin_amdgcn_mfma_f32_16x16x32_bf16(afr0, bfr, acc[0][nt], 0, 0, 0);
      acc[1][nt] = __builtin_amdgcn_mfma_f32_16x16x32_bf16(afr1, bfr, acc[1][nt], 0, 0, 0);
    }
    __syncthreads();
  }
  const int head = bn >> 6;
  const int Hmul = Nfull >> 6;
  float vs[2][4] = {};
  float vd[2][4] = {};
#pragma unroll
  for (int nt = 0; nt < 4; ++nt) {
    const float asv = a_s[head * 64 + nt * 16 + l16];
    const float adv = a_d[head * 64 + nt * 16 + l16];
#pragma unroll
    for (int mt = 0; mt < 2; ++mt)
#pragma unroll
      for (int reg = 0; reg < 4; ++reg) {
        unsigned short c = f2bf(acc[mt][nt][reg]);
        int r = bm + w * 32 + mt * 16 + quad * 4 + reg;
        if (r < NN) Cb[(size_t)r * Nfull + bn + nt * 16 + l16] = c;
        float hv = bf2f(c);
        vs[mt][reg] += hv * asv;
        vd[mt][reg] += hv * adv;
      }
  }
#pragma unroll
  for (int off = 1; off < 16; off <<= 1) {
#pragma unroll
    for (int mt = 0; mt < 2; ++mt)
#pragma unroll
      for (int reg = 0; reg < 4; ++reg) {
        vs[mt][reg] += __shfl_xor(vs[mt][reg], off, 64);
        vd[mt][reg] += __shfl_xor(vd[mt][reg], off, 64);
      }
  }
  if (l16 == 0) {
#pragma unroll
    for (int mt = 0; mt < 2; ++mt)
#pragma unroll
      for (int reg = 0; reg < 4; ++reg) {
        int r = bm + w * 32 + mt * 16 + quad * 4 + reg;
        if (r < NN) {
          als[(size_t)r * Hmul + head] = vs[mt][reg];
          ald[(size_t)r * Hmul + head] = vd[mt][reg];
          selfex[(size_t)r * Hmul + head] = __expf(leaky(vs[mt][reg] + vd[mt][reg]));
        }
      }
  }
}

// ================= CSR build (topology is layer-invariant) ==================
__global__ __launch_bounds__(256) void hist_k(const int* __restrict__ ei, int* deg) {
  int i = blockIdx.x * 256 + threadIdx.x;
  if (i < EE) atomicAdd(&deg[ei[EE + i]], 1);
}

__global__ __launch_bounds__(256) void scan1_k(const int* __restrict__ deg,
                                               int* __restrict__ incl,
                                               int* __restrict__ partial) {
  __shared__ int s[256];
  int t = threadIdx.x;
  int i = blockIdx.x * 256 + t;
  int v = (i < NN) ? deg[i] : 0;
  s[t] = v;
  __syncthreads();
  for (int off = 1; off < 256; off <<= 1) {
    int u = (t >= off) ? s[t - off] : 0;
    __syncthreads();
    s[t] += u;
    __syncthreads();
  }
  if (i < NN) incl[i] = s[t];
  if (t == 255) partial[blockIdx.x] = s[255];
}

__global__ void scan2_k(int* __restrict__ partial) {
  __shared__ int s[256];
  int t = threadIdx.x;
  int v = (t < NB) ? partial[t] : 0;
  s[t] = v;
  __syncthreads();
  for (int off = 1; off < 256; off <<= 1) {
    int u = (t >= off) ? s[t - off] : 0;
    __syncthreads();
    s[t] += u;
    __syncthreads();
  }
  if (t < NB) partial[t] = s[t] - v;  // exclusive
}

__global__ __launch_bounds__(256) void scan3_k(const int* __restrict__ deg,
                                               const int* __restrict__ incl,
                                               const int* __restrict__ partial,
                                               int* __restrict__ rowptr,
                                               int* __restrict__ cursor) {
  int i = blockIdx.x * 256 + threadIdx.x;
  if (i >= NN) return;
  int r = partial[blockIdx.x] + incl[i] - deg[i];
  rowptr[i] = r;
  cursor[i] = r;
}

__global__ __launch_bounds__(256) void scatter_k(const int* __restrict__ ei,
                                                 int* __restrict__ cursor,
                                                 int* __restrict__ csr_src,
                                                 int* __restrict__ csr_dst) {
  int i = blockIdx.x * 256 + threadIdx.x;
  if (i >= EE) return;
  int d = ei[EE + i];
  int p = atomicAdd(&cursor[d], 1);
  csr_src[p] = ei[i];
  csr_dst[p] = d;
}

// ====== per-CSR-slot unnormalized exp, AoS float4 (H=4) =====================
__global__ __launch_bounds__(256) void edge_exp4_k(const int* __restrict__ csr_src,
                                                   const int* __restrict__ csr_dst,
                                                   const float* __restrict__ als,
                                                   const float* __restrict__ ald,
                                                   float4* __restrict__ ex4) {
  int i = blockIdx.x * 256 + threadIdx.x;
  if (i >= EE) return;
  int s = csr_src[i], d = csr_dst[i];
  const float4 as4 = *(const float4*)(als + (size_t)s * 4);
  const float4 ad4 = *(const float4*)(ald + (size_t)d * 4);
  float4 e;
  e.x = __expf(leaky(as4.x + ad4.x));
  e.y = __expf(leaky(as4.y + ad4.y));
  e.z = __expf(leaky(as4.z + ad4.z));
  e.w = __expf(leaky(as4.w + ad4.w));
  ex4[i] = e;
}

__global__ __launch_bounds__(256) void edge_exp1_k(const int* __restrict__ csr_src,
                                                   const int* __restrict__ csr_dst,
                                                   const float* __restrict__ als,
                                                   const float* __restrict__ ald,
                                                   float* __restrict__ ex1) {
  int i = blockIdx.x * 256 + threadIdx.x;
  if (i >= EE) return;
  ex1[i] = __expf(leaky(als[csr_src[i]] + ald[csr_dst[i]]));
}

// ====== gather-aggregate + inline den-sum, H=4: wave/dst ====================
// 4 edge-slots x 16 lanes x 32B (full 512B row per edge within one wave —
// whole cache lines consumed where they land). Zero atomics.
__global__ __launch_bounds__(256) void aggr4c_k(const int* __restrict__ rowptr,
                                                const int* __restrict__ deg,
                                                const int* __restrict__ csr_src,
                                                const float4* __restrict__ ex4,
                                                const float* __restrict__ selfex,
                                                const uint4* __restrict__ hb4,
                                                const float* __restrict__ bias,
                                                uint4* __restrict__ out4) {
  const int dst = blockIdx.x * 4 + (threadIdx.x >> 6);
  const int lane = threadIdx.x & 63;
  const int slot = lane >> 4;
  const int l16 = lane & 15;
  const int head = l16 >> 2;
  const int rs = rowptr[dst];
  const int dg = deg[dst];

  float acc[16] = {};
  float dsum = 0.f;
  if (slot == 0) {  // self-loop (unnormalized)
    float a = selfex[dst * 4 + head];
    dsum += a;
    uint4 v0 = hb4[(size_t)dst * 32 + l16 * 2];
    uint4 v1 = hb4[(size_t)dst * 32 + l16 * 2 + 1];
    accum8(a, v0, acc);
    accum8(a, v1, acc + 8);
  }
  int j = slot;
  for (; j + 4 < dg; j += 8) {
    int s0 = csr_src[rs + j];
    int s1 = csr_src[rs + j + 4];
    float4 av0 = ex4[rs + j];
    float4 av1 = ex4[rs + j + 4];
    uint4 va0 = hb4[(size_t)s0 * 32 + l16 * 2];
    uint4 vb0 = hb4[(size_t)s0 * 32 + l16 * 2 + 1];
    uint4 va1 = hb4[(size_t)s1 * 32 + l16 * 2];
    uint4 vb1 = hb4[(size_t)s1 * 32 + l16 * 2 + 1];
    float a0 = selh(av0, head);
    float a1 = selh(av1, head);
    dsum += a0 + a1;
    accum8(a0, va0, acc);
    accum8(a0, vb0, acc + 8);
    accum8(a1, va1, acc);
    accum8(a1, vb1, acc + 8);
  }
  for (; j < dg; j += 4) {
    int s0 = csr_src[rs + j];
    float4 av0 = ex4[rs + j];
    uint4 va0 = hb4[(size_t)s0 * 32 + l16 * 2];
    uint4 vb0 = hb4[(size_t)s0 * 32 + l16 * 2 + 1];
    float a0 = selh(av0, head);
    dsum += a0;
    accum8(a0, va0, acc);
    accum8(a0, vb0, acc + 8);
  }
#pragma unroll
  for (int k = 0; k < 16; ++k) {
    acc[k] += __shfl_xor(acc[k], 16, 64);
    acc[k] += __shfl_xor(acc[k], 32, 64);
  }
  dsum += __shfl_xor(dsum, 16, 64);
  dsum += __shfl_xor(dsum, 32, 64);
  if (slot == 0) {  // channels [l16*16, l16*16+16), relu (both H=4 layers)
    const float inv = 1.f / (dsum + 1e-16f);
    const float* bz = bias + l16 * 16;
    uint4 o0, o1;
    float c0, c1;
    c0 = fmaxf(acc[0] * inv + bz[0], 0.f);   c1 = fmaxf(acc[1] * inv + bz[1], 0.f);
    o0.x = ((unsigned int)f2bf(c1) << 16) | f2bf(c0);
    c0 = fmaxf(acc[2] * inv + bz[2], 0.f);   c1 = fmaxf(acc[3] * inv + bz[3], 0.f);
    o0.y = ((unsigned int)f2bf(c1) << 16) | f2bf(c0);
    c0 = fmaxf(acc[4] * inv + bz[4], 0.f);   c1 = fmaxf(acc[5] * inv + bz[5], 0.f);
    o0.z = ((unsigned int)f2bf(c1) << 16) | f2bf(c0);
    c0 = fmaxf(acc[6] * inv + bz[6], 0.f);   c1 = fmaxf(acc[7] * inv + bz[7], 0.f);
    o0.w = ((unsigned int)f2bf(c1) << 16) | f2bf(c0);
    c0 = fmaxf(acc[8] * inv + bz[8], 0.f);   c1 = fmaxf(acc[9] * inv + bz[9], 0.f);
    o1.x = ((unsigned int)f2bf(c1) << 16) | f2bf(c0);
    c0 = fmaxf(acc[10] * inv + bz[10], 0.f); c1 = fmaxf(acc[11] * inv + bz[11], 0.f);
    o1.y = ((unsigned int)f2bf(c1) << 16) | f2bf(c0);
    c0 = fmaxf(acc[12] * inv + bz[12], 0.f); c1 = fmaxf(acc[13] * inv + bz[13], 0.f);
    o1.z = ((unsigned int)f2bf(c1) << 16) | f2bf(c0);
    c0 = fmaxf(acc[14] * inv + bz[14], 0.f); c1 = fmaxf(acc[15] * inv + bz[15], 0.f);
    o1.w = ((unsigned int)f2bf(c1) << 16) | f2bf(c0);
    out4[(size_t)dst * 32 + l16 * 2] = o0;
    out4[(size_t)dst * 32 + l16 * 2 + 1] = o1;
  }
}

// ====== gather-aggregate + inline den-sum, H=1: wave/dst, 8 slots x 8 lanes ==
__global__ __launch_bounds__(256) void aggr1c_k(const int* __restrict__ rowptr,
                                                const int* __restrict__ deg,
                                                const int* __restrict__ csr_src,
                                                const float* __restrict__ ex1,
                                                const float* __restrict__ selfex,
                                                const uint4* __restrict__ hb4,
                                                const float* __restrict__ bias,
                                                float* __restrict__ out) {
  const int dst = blockIdx.x * 4 + (threadIdx.x >> 6);
  const int lane = threadIdx.x & 63;
  const int slot = lane >> 3;
  const int c8 = lane & 7;
  const int rs = rowptr[dst];
  const int dg = deg[dst];

  float acc[8] = {};
  float dsum = 0.f;
  if (slot == 0) {
    float a = selfex[dst];
    dsum += a;
    uint4 v = hb4[(size_t)dst * 8 + c8];
    accum8(a, v, acc);
  }
  for (int j = slot; j < dg; j += 8) {
    int s = csr_src[rs + j];
    float a = ex1[rs + j];
    dsum += a;
    uint4 v = hb4[(size_t)s * 8 + c8];
    accum8(a, v, acc);
  }
#pragma unroll
  for (int k = 0; k < 8; ++k) {
    acc[k] += __shfl_xor(acc[k], 8, 64);
    acc[k] += __shfl_xor(acc[k], 16, 64);
    acc[k] += __shfl_xor(acc[k], 32, 64);
  }
  dsum += __shfl_xor(dsum, 8, 64);
  dsum += __shfl_xor(dsum, 16, 64);
  dsum += __shfl_xor(dsum, 32, 64);
  if (slot == 0) {  // no relu on layer 2; fp32 out
    const float inv = 1.f / (dsum + 1e-16f);
    const float4 bz0 = *(const float4*)(bias + c8 * 8);
    const float4 bz1 = *(const float4*)(bias + c8 * 8 + 4);
    float4 o0 = make_float4(acc[0] * inv + bz0.x, acc[1] * inv + bz0.y,
                            acc[2] * inv + bz0.z, acc[3] * inv + bz0.w);
    float4 o1 = make_float4(acc[4] * inv + bz1.x, acc[5] * inv + bz1.y,
                            acc[6] * inv + bz1.z, acc[7] * inv + bz1.w);
    *(float4*)(out + (size_t)dst * 64 + c8 * 8) = o0;
    *(float4*)(out + (size_t)dst * 64 + c8 * 8 + 4) = o1;
  }
}

// ---- prep: fp32 x -> packed bf16 ----
__global__ __launch_bounds__(256) void castx_k(const float2* __restrict__ x2,
                                               unsigned int* __restrict__ xb_u) {
  int i = blockIdx.x * 256 + threadIdx.x;
  if (i >= NN * 64) return;
  float2 v = x2[i];
  xb_u[i] = ((unsigned int)f2bf(v.y) << 16) | f2bf(v.x);
}

// ---- prep: W[K][N] fp32 -> Wt[N][K] bf16 ----
__global__ __launch_bounds__(64) void trw_k(const float* __restrict__ W,
                                            unsigned short* __restrict__ Wt, int K, int N) {
  int k = blockIdx.x;
  int n = blockIdx.y * 64 + threadIdx.x;
  Wt[(size_t)n * K + k] = f2bf(W[(size_t)k * N + n]);
}

// column sums of final [N,64] fp32 -> g[64]
__global__ __launch_bounds__(256) void colsum_k(const float* __restrict__ h2,
                                                float* __restrict__ g) {
  __shared__ float s[256];
  int tid = threadIdx.x;
  int c = tid & 63, rg = tid >> 6;
  float acc = 0.f;
  for (int n = blockIdx.x * 4 + rg; n < NN; n += gridDim.x * 4)
    acc += h2[n * 64 + c];
  s[tid] = acc;
  __syncthreads();
  if (tid < 64) atomicAdd(&g[c], s[c] + s[64 + c] + s[128 + c] + s[192 + c]);
}

__global__ void head_k(const float* __restrict__ g, const float* __restrict__ hw,
                       const float* __restrict__ hb, float* __restrict__ out) {
  int o = threadIdx.x;  // 64 threads
  float acc = 0.f;
  const float invN = 1.0f / (float)NN;
#pragma unroll 8
  for (int c = 0; c < 64; ++c) acc += (g[c] * invN) * hw[c * 64 + o];
  out[o] = acc + hb[o];
}

extern "C" void kernel_launch(void* const* d_in, const int* in_sizes, int n_in,
                              void* d_out, int out_size, void* d_ws, size_t ws_size,
                              hipStream_t stream) {
  const float* x   = (const float*)d_in[0];
  const int*   ei  = (const int*)d_in[1];
  const float* W0  = (const float*)d_in[2];
  const float* a0s = (const float*)d_in[3];
  const float* a0d = (const float*)d_in[4];
  const float* b0  = (const float*)d_in[5];
  const float* W1  = (const float*)d_in[6];
  const float* a1s = (const float*)d_in[7];
  const float* a1d = (const float*)d_in[8];
  const float* b1  = (const float*)d_in[9];
  const float* W2  = (const float*)d_in[10];
  const float* a2s = (const float*)d_in[11];
  const float* a2d = (const float*)d_in[12];
  const float* b2  = (const float*)d_in[13];
  const float* hw  = (const float*)d_in[14];
  const float* hb  = (const float*)d_in[15];
  float* out = (float*)d_out;

  char* w = (char*)d_ws;
  unsigned short* xb   = (unsigned short*)w; w += (size_t)NN * 128 * 2;
  unsigned short* bufG = (unsigned short*)w; w += (size_t)NN * 256 * 2;
  unsigned short* bufA = (unsigned short*)w; w += (size_t)NN * 256 * 2;
  float* bufF = (float*)w;                   w += (size_t)NN * 64 * 4;
  unsigned short* W0t = (unsigned short*)w;  w += 256 * 128 * 2;
  unsigned short* W1t = (unsigned short*)w;  w += 256 * 256 * 2;
  unsigned short* W2t = (unsigned short*)w;  w += 64 * 256 * 2;
  float* als  = (float*)w;    w += (size_t)NN * 4 * 4;
  float* ald  = (float*)w;    w += (size_t)NN * 4 * 4;
  float* sfx  = (float*)w;    w += (size_t)NN * 4 * 4;
  float4* ex4 = (float4*)w;   w += (size_t)EE * 16;  // reused as ex1 plane for H=1
  int* deg     = (int*)w;     w += (size_t)NN * 4;
  int* rowptr  = (int*)w;     w += (size_t)NN * 4;
  int* cursor  = (int*)w;     w += (size_t)NN * 4;
  int* incl    = (int*)w;     w += (size_t)NN * 4;
  int* partial = (int*)w;     w += 256 * 4;
  int* csr_src = (int*)w;     w += (size_t)EE * 4;
  int* csr_dst = (int*)w;     w += (size_t)EE * 4;
  float* g    = (float*)w;    w += 256;

  // ---- CSR build (shared by all 3 layers) ----
  hipMemsetAsync(deg, 0, (size_t)NN * 4, stream);
  hist_k<<<(EE + 255) / 256, 256, 0, stream>>>(ei, deg);
  scan1_k<<<NB, 256, 0, stream>>>(deg, incl, partial);
  scan2_k<<<1, 256, 0, stream>>>(partial);
  scan3_k<<<NB, 256, 0, stream>>>(deg, incl, partial, rowptr, cursor);
  scatter_k<<<(EE + 255) / 256, 256, 0, stream>>>(ei, cursor, csr_src, csr_dst);

  // ---- prep casts/transposes ----
  castx_k<<<(NN * 64 + 255) / 256, 256, 0, stream>>>((const float2*)x, (unsigned int*)xb);
  trw_k<<<dim3(128, 4), 64, 0, stream>>>(W0, W0t, 128, 256);
  trw_k<<<dim3(256, 4), 64, 0, stream>>>(W1, W1t, 256, 256);
  trw_k<<<dim3(256, 1), 64, 0, stream>>>(W2, W2t, 256, 64);

  const int GX = (NN + 127) / 128;
  const int GA = NN / 4;   // 12500 exact
  const int GE = EE / 256; // 3125 exact

  auto layer4 = [&](const unsigned short* in, int K, const unsigned short* Wt,
                    const float* a_s, const float* a_d, const float* bias,
                    unsigned short* hbuf, unsigned short* obuf) {
    gemm_bf16_k<<<dim3(GX, 4), 256, 0, stream>>>(in, Wt, hbuf, K, 256,
                                                 a_s, a_d, als, ald, sfx);
    edge_exp4_k<<<GE, 256, 0, stream>>>(csr_src, csr_dst, als, ald, ex4);
    aggr4c_k<<<GA, 256, 0, stream>>>(rowptr, deg, csr_src, ex4, sfx,
                                     (const uint4*)hbuf, bias, (uint4*)obuf);
  };

  // layers 0 and 1 (H=4)
  layer4(xb, 128, W0t, a0s, a0d, b0, bufG, bufA);
  layer4(bufA, 256, W1t, a1s, a1d, b1, bufG, bufA);

  // layer 2 (H=1)
  gemm_bf16_k<<<dim3(GX, 1), 256, 0, stream>>>(bufA, W2t, bufG, 256, 64,
                                               a2s, a2d, als, ald, sfx);
  edge_exp1_k<<<GE, 256, 0, stream>>>(csr_src, csr_dst, als, ald, (float*)ex4);
  aggr1c_k<<<GA, 256, 0, stream>>>(rowptr, deg, csr_src, (const float*)ex4, sfx,
                                   (const uint4*)bufG, b2, bufF);

  hipMemsetAsync(g, 0, 64 * 4, stream);
  colsum_k<<<256, 256, 0, stream>>>(bufF, g);
  head_k<<<1, 64, 0, stream>>>(g, hw, hb, out);
}